// Round 1
// baseline (210.404 us; speedup 1.0000x reference)
//
#include <hip/hip_runtime.h>

#define NB 512
#define NG 100
#define NP 100
#define NE 128
#define NH 8
#define LDST 136   // bf16 elems per LDS row (pad 128 -> 136: 2-way-free banks)

typedef __attribute__((ext_vector_type(8))) short short8;
typedef __attribute__((ext_vector_type(4))) short short4v;
typedef __attribute__((ext_vector_type(4))) float f32x4;

__device__ __forceinline__ short f2bf(float f) {
    union { float f; unsigned u; } v; v.f = f;
    unsigned r = v.u + 0x7FFFu + ((v.u >> 16) & 1u);
    return (short)(r >> 16);
}

// ---- prep: transpose weights to bf16 row-major [n][k] in ws ----
__global__ void prep_kernel(const float* __restrict__ Wq, const float* __restrict__ Wk,
                            const float* __restrict__ Wv, const float* __restrict__ Wc,
                            short* __restrict__ WqT2, short* __restrict__ WkT,
                            short* __restrict__ WvT, short* __restrict__ WcT,
                            float* __restrict__ wqlast)
{
    int idx = blockIdx.x * 256 + threadIdx.x;   // 65536 total
    int mat = idx >> 14;
    int e   = idx & 16383;
    int k = e >> 7, n = e & 127;
    float v;
    short* dst;
    if (mat == 0)      { v = Wq[(128 + k) * 128 + n]; dst = WqT2; }
    else if (mat == 1) { v = Wk[k * 128 + n];         dst = WkT;  }
    else if (mat == 2) { v = Wv[k * 128 + n];         dst = WvT;  }
    else               { v = Wc[k * 128 + n];         dst = WcT;  }
    dst[n * 128 + k] = f2bf(v);
    if (idx < 128) wqlast[idx] = Wq[256 * 128 + idx];
}

// ---- fused main kernel: one block per batch ----
__global__ __launch_bounds__(512, 2)
void fused_kernel(const float* __restrict__ input1, const float* __restrict__ input2,
                  const float* __restrict__ rem, const float* __restrict__ mask,
                  const float* __restrict__ enc, const float* __restrict__ Wq,
                  const float* __restrict__ bc,
                  const short* __restrict__ WqT2, const short* __restrict__ WkT,
                  const short* __restrict__ WvT, const short* __restrict__ WcT,
                  const float* __restrict__ wqlast, float* __restrict__ out)
{
    extern __shared__ short smem[];
    short* sEnc = smem;                 // [100][136] encoded nodes bf16 (kept to the end)
    short* sK   = sEnc + 100 * LDST;    // [100][136] K proj; later aliased as Mh
    short* sQ   = sK   + 100 * LDST;    // [100][136] Q proj; later aliased as out_concat
    short* sVT  = sQ   + 100 * LDST;    // [128][136] V^T; first used as input2 staging
    short* sWs  = sVT  + 128 * LDST;    // [8][16][136] per-wave P-relayout scratch
    float* sQ1  = (float*)(sWs + 8 * 16 * LDST);  // [4][128] q1 partial sums

    const int b    = blockIdx.x;
    const int tid  = threadIdx.x;
    const int wave = tid >> 6, lane = tid & 63;
    const int l16  = lane & 15, lh = lane >> 4;

    // ---------- Phase 0: stage enc + input2 (f32->bf16), q1 partials ----------
    {
        const float4* e4 = (const float4*)(enc    + (size_t)b * NP * NE);
        const float4* i4 = (const float4*)(input2 + (size_t)b * NG * NE);
        for (int idx = tid; idx < 100 * 32; idx += 512) {
            int row = idx >> 5, c = idx & 31;
            float4 v = e4[idx];
            short4v h = { f2bf(v.x), f2bf(v.y), f2bf(v.z), f2bf(v.w) };
            *(short4v*)(sEnc + row * LDST + c * 4) = h;
            float4 w = i4[idx];
            short4v h2 = { f2bf(w.x), f2bf(w.y), f2bf(w.z), f2bf(w.w) };
            *(short4v*)(sVT + row * LDST + c * 4) = h2;
        }
        // q1[n] = input1[b] . Wq[0:128, n], split over 4 partials
        {
            int n = tid & 127, part = tid >> 7;  // part 0..3
            const float* i1 = input1 + (size_t)b * NE;
            float s = 0.f;
            #pragma unroll 8
            for (int k = part * 32; k < part * 32 + 32; ++k)
                s += i1[k] * Wq[k * NE + n];
            sQ1[part * 128 + n] = s;
        }
    }
    __syncthreads();

    // ---------- Phase 1: Q = [in2 @ Wq2] + q1 + rem*wqlast  -> sQ ----------
    for (int t = wave; t < 56; t += 8) {
        int mt = t >> 3, nt = t & 7;
        f32x4 acc = {0.f, 0.f, 0.f, 0.f};
        #pragma unroll
        for (int ks = 0; ks < 4; ++ks) {
            short8 a = *(const short8*)(sVT + (mt * 16 + l16) * LDST + ks * 32 + lh * 8);
            short8 w = *(const short8*)(WqT2 + (nt * 16 + l16) * NE + ks * 32 + lh * 8);
            acc = __builtin_amdgcn_mfma_f32_16x16x32_bf16(a, w, acc, 0, 0, 0);
        }
        int n = nt * 16 + l16;
        float q1n = sQ1[n] + sQ1[128 + n] + sQ1[256 + n] + sQ1[384 + n];
        float wl = wqlast[n];
        #pragma unroll
        for (int r = 0; r < 4; ++r) {
            int g = mt * 16 + lh * 4 + r;
            if (g < NG) {
                float rv = rem[(size_t)b * NG + g];
                sQ[g * LDST + n] = f2bf(acc[r] + q1n + rv * wl);
            }
        }
    }
    __syncthreads();

    // ---------- Phase 2: K -> sK (row-major), V -> sVT (transposed) ----------
    for (int t = wave; t < 112; t += 8) {
        int isV = t >= 56;
        int tt = t - (isV ? 56 : 0);
        int mt = tt >> 3, nt = tt & 7;
        const short* WT = isV ? WvT : WkT;
        f32x4 acc = {0.f, 0.f, 0.f, 0.f};
        #pragma unroll
        for (int ks = 0; ks < 4; ++ks) {
            short8 a = *(const short8*)(sEnc + (mt * 16 + l16) * LDST + ks * 32 + lh * 8);
            short8 w = *(const short8*)(WT + (nt * 16 + l16) * NE + ks * 32 + lh * 8);
            acc = __builtin_amdgcn_mfma_f32_16x16x32_bf16(a, w, acc, 0, 0, 0);
        }
        int n = nt * 16 + l16;
        if (!isV) {
            #pragma unroll
            for (int r = 0; r < 4; ++r) {
                int p = mt * 16 + lh * 4 + r;
                if (p < NP) sK[p * LDST + n] = f2bf(acc[r]);
            }
        } else {
            int p0 = mt * 16 + lh * 4;
            if (p0 < NP) {  // p0 multiple of 4; p0<100 => p0+3<=99
                short4v h = { f2bf(acc[0]), f2bf(acc[1]), f2bf(acc[2]), f2bf(acc[3]) };
                *(short4v*)(sVT + n * LDST + p0) = h;
            }
        }
    }
    // zero V^T columns p=100..135 (padding used by PV MFMA)
    for (int idx = tid; idx < 128 * 36; idx += 512) {
        int n = idx / 36, c = 100 + idx % 36;
        sVT[n * LDST + c] = 0;
    }
    __syncthreads();

    // ---------- Phase 3: per-head attention (waves 0..6, wave w owns g-tile w) ----------
    float mk[7][4];
    if (wave < 7) {
        const int gt = wave;
        #pragma unroll
        for (int pt = 0; pt < 7; ++pt)
            #pragma unroll
            for (int r = 0; r < 4; ++r) {
                int g = gt * 16 + lh * 4 + r, p = pt * 16 + l16;
                mk[pt][r] = (g < NG && p < NP) ? mask[((size_t)b * NG + g) * NP + p]
                                               : -__builtin_inff();
            }
        short* myW = sWs + wave * 16 * LDST;
        for (int i = lane; i < 16 * 24; i += 64) {     // zero cols 112..135 once
            int rr = i / 24, c = 112 + i % 24;
            myW[rr * LDST + c] = 0;
        }

        for (int h = 0; h < NH; ++h) {
            // QK^T: K-dim = 16, padded to 32 with zero fragments
            short8 aq = {0,0,0,0,0,0,0,0};
            if (lh < 2) aq = *(const short8*)(sQ + (gt * 16 + l16) * LDST + h * 16 + lh * 8);
            f32x4 sc[7];
            #pragma unroll
            for (int pt = 0; pt < 7; ++pt) {
                short8 kk = {0,0,0,0,0,0,0,0};
                if (lh < 2) kk = *(const short8*)(sK + (pt * 16 + l16) * LDST + h * 16 + lh * 8);
                f32x4 z = {0.f, 0.f, 0.f, 0.f};
                sc[pt] = __builtin_amdgcn_mfma_f32_16x16x32_bf16(aq, kk, z, 0, 0, 0);
            }
            // scale + mask (select, never add, at invalid p) ; softmax over p
            float vals[7][4];
            #pragma unroll
            for (int pt = 0; pt < 7; ++pt) {
                bool pv = (pt * 16 + l16) < NP;
                #pragma unroll
                for (int r = 0; r < 4; ++r)
                    vals[pt][r] = pv ? sc[pt][r] * 0.25f + mk[pt][r] : -__builtin_inff();
            }
            #pragma unroll
            for (int r = 0; r < 4; ++r) {
                float m = vals[0][r];
                #pragma unroll
                for (int pt = 1; pt < 7; ++pt) m = fmaxf(m, vals[pt][r]);
                #pragma unroll
                for (int d = 1; d < 16; d <<= 1) m = fmaxf(m, __shfl_xor(m, d, 64));
                float s = 0.f;
                #pragma unroll
                for (int pt = 0; pt < 7; ++pt) {
                    float e = ((pt * 16 + l16) < NP) ? __expf(vals[pt][r] - m) : 0.f;
                    vals[pt][r] = e; s += e;
                }
                #pragma unroll
                for (int d = 1; d < 16; d <<= 1) s += __shfl_xor(s, d, 64);
                float inv = 1.f / s;
                #pragma unroll
                for (int pt = 0; pt < 7; ++pt) vals[pt][r] *= inv;
            }
            // relayout P (D-frag) -> A-frag via wave-private LDS scratch
            #pragma unroll
            for (int pt = 0; pt < 7; ++pt)
                #pragma unroll
                for (int r = 0; r < 4; ++r)
                    myW[(lh * 4 + r) * LDST + pt * 16 + l16] = f2bf(vals[pt][r]);
            // PV: out[g][k] = sum_p P[g][p] * V[p][k]
            f32x4 o = {0.f, 0.f, 0.f, 0.f};
            #pragma unroll
            for (int ps = 0; ps < 4; ++ps) {
                short8 a  = *(const short8*)(myW + l16 * LDST + ps * 32 + lh * 8);
                short8 vv = *(const short8*)(sVT + (h * 16 + l16) * LDST + ps * 32 + lh * 8);
                o = __builtin_amdgcn_mfma_f32_16x16x32_bf16(a, vv, o, 0, 0, 0);
            }
            // write out_concat into sQ's head-h columns (already consumed by this task's QK)
            #pragma unroll
            for (int r = 0; r < 4; ++r) {
                int g = gt * 16 + lh * 4 + r;
                if (g < NG) sQ[g * LDST + h * 16 + l16] = f2bf(o[r]);
            }
        }
    }
    __syncthreads();

    // ---------- Phase 4: Mh = out_concat @ Wc + bc -> sK (aliased as Mh) ----------
    for (int t = wave; t < 56; t += 8) {
        int mt = t >> 3, nt = t & 7;
        f32x4 acc = {0.f, 0.f, 0.f, 0.f};
        #pragma unroll
        for (int ks = 0; ks < 4; ++ks) {
            short8 a = *(const short8*)(sQ + (mt * 16 + l16) * LDST + ks * 32 + lh * 8);
            short8 w = *(const short8*)(WcT + (nt * 16 + l16) * NE + ks * 32 + lh * 8);
            acc = __builtin_amdgcn_mfma_f32_16x16x32_bf16(a, w, acc, 0, 0, 0);
        }
        int n = nt * 16 + l16;
        float bias = bc[n];
        #pragma unroll
        for (int r = 0; r < 4; ++r) {
            int g = mt * 16 + lh * 4 + r;
            if (g < NG) sK[g * LDST + n] = f2bf(acc[r] + bias);
        }
    }
    __syncthreads();

    // ---------- Phase 5: pointer scores + tanh clip + softmax -> out ----------
    if (wave < 7) {
        const int gt = wave;
        short8 afr[4];
        #pragma unroll
        for (int ks = 0; ks < 4; ++ks)
            afr[ks] = *(const short8*)(sK + (gt * 16 + l16) * LDST + ks * 32 + lh * 8);
        float vals[7][4];
        #pragma unroll
        for (int pt = 0; pt < 7; ++pt) {
            f32x4 acc = {0.f, 0.f, 0.f, 0.f};
            #pragma unroll
            for (int ks = 0; ks < 4; ++ks) {
                short8 e8 = *(const short8*)(sEnc + (pt * 16 + l16) * LDST + ks * 32 + lh * 8);
                acc = __builtin_amdgcn_mfma_f32_16x16x32_bf16(afr[ks], e8, acc, 0, 0, 0);
            }
            bool pv = (pt * 16 + l16) < NP;
            #pragma unroll
            for (int r = 0; r < 4; ++r) {
                float x = acc[r] * 0.08838834764831845f;     // 1/sqrt(128)
                float th = 1.f - 2.f / (__expf(2.f * x) + 1.f);  // tanh
                vals[pt][r] = pv ? 10.f * th + mk[pt][r] : -__builtin_inff();
            }
        }
        #pragma unroll
        for (int r = 0; r < 4; ++r) {
            float m = vals[0][r];
            #pragma unroll
            for (int pt = 1; pt < 7; ++pt) m = fmaxf(m, vals[pt][r]);
            #pragma unroll
            for (int d = 1; d < 16; d <<= 1) m = fmaxf(m, __shfl_xor(m, d, 64));
            float s = 0.f;
            #pragma unroll
            for (int pt = 0; pt < 7; ++pt) {
                float e = ((pt * 16 + l16) < NP) ? __expf(vals[pt][r] - m) : 0.f;
                vals[pt][r] = e; s += e;
            }
            #pragma unroll
            for (int d = 1; d < 16; d <<= 1) s += __shfl_xor(s, d, 64);
            float inv = 1.f / s;
            #pragma unroll
            for (int pt = 0; pt < 7; ++pt) vals[pt][r] *= inv;
        }
        #pragma unroll
        for (int pt = 0; pt < 7; ++pt) {
            int p = pt * 16 + l16;
            if (p < NP) {
                #pragma unroll
                for (int r = 0; r < 4; ++r) {
                    int g = gt * 16 + lh * 4 + r;
                    if (g < NG) out[((size_t)b * NG + g) * NP + p] = vals[pt][r];
                }
            }
        }
    }
}

#define SMEM_BYTES ((3 * 100 * LDST + 128 * LDST + 8 * 16 * LDST) * 2 + 512 * 4)

extern "C" void kernel_launch(void* const* d_in, const int* in_sizes, int n_in,
                              void* d_out, int out_size, void* d_ws, size_t ws_size,
                              hipStream_t stream)
{
    const float* input1 = (const float*)d_in[0];
    const float* input2 = (const float*)d_in[1];
    const float* rem    = (const float*)d_in[2];
    const float* mask   = (const float*)d_in[3];
    const float* enc    = (const float*)d_in[4];
    const float* Wq     = (const float*)d_in[5];
    const float* Wk     = (const float*)d_in[6];
    const float* Wv     = (const float*)d_in[7];
    const float* Wc     = (const float*)d_in[8];
    const float* bc     = (const float*)d_in[9];

    short* WqT2   = (short*)d_ws;
    short* WkT    = WqT2 + 16384;
    short* WvT    = WkT + 16384;
    short* WcT    = WvT + 16384;
    float* wqlast = (float*)(WcT + 16384);

    prep_kernel<<<256, 256, 0, stream>>>(Wq, Wk, Wv, Wc, WqT2, WkT, WvT, WcT, wqlast);

    hipFuncSetAttribute((const void*)fused_kernel,
                        hipFuncAttributeMaxDynamicSharedMemorySize, SMEM_BYTES);
    fused_kernel<<<NB, 512, SMEM_BYTES, stream>>>(
        input1, input2, rem, mask, enc, Wq, bc,
        WqT2, WkT, WvT, WcT, wqlast, (float*)d_out);
}